// Round 13
// baseline (336.819 us; speedup 1.0000x reference)
//
#include <hip/hip_runtime.h>
#include <hip/hip_bf16.h>
#include <math.h>
#include <stdint.h>

typedef unsigned short u16;
typedef __attribute__((ext_vector_type(8))) short bf16x8;
typedef __attribute__((ext_vector_type(4))) float f32x4;
typedef __attribute__((address_space(3))) void* as3_void;
typedef const __attribute__((address_space(1))) void* as1_cvoid;

__device__ inline u16 f2bf(float f) {
    union { float f; unsigned u; } v; v.f = f;
    unsigned r = v.u + 0x7FFFu + ((v.u >> 16) & 1u);   // round-to-nearest-even
    return (u16)(r >> 16);
}
__device__ inline float bf2f(u16 h) {
    unsigned u = ((unsigned)h) << 16;
    return __builtin_bit_cast(float, u);
}
// fast GELU (tanh form via sigmoid): x * sigma(1.5957691*(x+0.044715x^3))
__device__ inline float gelu_fast(float v) {
    float t = v * fmaf(0.07135702f, v * v, 1.5957691f);
    return v / (1.f + __expf(-t));
}

// DPP helper
template<int CTRL, int RM>
__device__ inline float dpp_mov(float v) {
    return __builtin_bit_cast(float, __builtin_amdgcn_update_dpp(
        0, __builtin_bit_cast(int, v), CTRL, RM, 0xf, false));
}
__device__ inline float wave_sum(float v) {
    v += dpp_mov<0x111, 0xf>(v);
    v += dpp_mov<0x112, 0xf>(v);
    v += dpp_mov<0x114, 0xf>(v);
    v += dpp_mov<0x118, 0xf>(v);
    v += dpp_mov<0x142, 0xa>(v);
    v += dpp_mov<0x143, 0xc>(v);
    return v;                      // lane 63 holds total
}

#define MFMA16(a, b, c) __builtin_amdgcn_mfma_f32_16x16x32_bf16(a, b, c, 0, 0, 0)

// ---------------------------------------------------------------------------
// prep_transpose: src [Dd][Rr] f32 -> dst [Rr][Dd] bf16, 32x32 LDS tiles.
// ---------------------------------------------------------------------------
__global__ __launch_bounds__(256)
void prep_transpose(const float* __restrict__ src, u16* __restrict__ dst,
                    int Rr, int Dd)
{
    __shared__ float t[32][33];
    int tilesR = Rr >> 5;
    int bi = blockIdx.x / tilesR;
    int bj = blockIdx.x - bi * tilesR;
    int d0 = bi * 32, r0 = bj * 32;
    int tr = threadIdx.x >> 3, c4 = threadIdx.x & 7;
    float4 v = *(const float4*)&src[(size_t)(d0 + tr) * Rr + r0 + c4 * 4];
    t[tr][c4 * 4 + 0] = v.x; t[tr][c4 * 4 + 1] = v.y;
    t[tr][c4 * 4 + 2] = v.z; t[tr][c4 * 4 + 3] = v.w;
    __syncthreads();
    short4 o;
    o.x = (short)f2bf(t[c4 * 4 + 0][tr]);
    o.y = (short)f2bf(t[c4 * 4 + 1][tr]);
    o.z = (short)f2bf(t[c4 * 4 + 2][tr]);
    o.w = (short)f2bf(t[c4 * 4 + 3][tr]);
    *(short4*)&dst[(size_t)(r0 + tr) * Dd + d0 + c4 * 4] = o;
}

// ---------------------------------------------------------------------------
// prep_cast: w1o/w2o bf16 casts + bias rows
// ---------------------------------------------------------------------------
__global__ __launch_bounds__(256)
void prep_cast(const float* __restrict__ Win1, const float* __restrict__ Wout1,
               const float* __restrict__ Win2, const float* __restrict__ Wout2,
               u16* __restrict__ w1o, u16* __restrict__ w2o,
               float* __restrict__ b1, float* __restrict__ b2)
{
    int idx = blockIdx.x * 256 + threadIdx.x;
    if (idx < 2097152) w1o[idx] = f2bf(Wout1[idx]);   // [4096,512]
    if (idx < 524288)  w2o[idx] = f2bf(Wout2[idx]);   // [1024,512]
    if (idx < 512) {
        b1[idx] = Win1[(size_t)1024 * 512 + idx];
        b2[idx] = Win2[(size_t)4096 * 512 + idx];
    }
}

// ---------------------------------------------------------------------------
// k1_proj: s = x@proj (f32) + x->bf16 cast. grid-stride, 512 blocks.
// ---------------------------------------------------------------------------
__global__ __launch_bounds__(256)
void k1_proj(const float* __restrict__ x, const float* __restrict__ proj,
             u16* __restrict__ xb, float* __restrict__ sbuf, int Ntok)
{
    __shared__ float plt[16 * 1024];
    const int tid = threadIdx.x;
    #pragma unroll
    for (int k = 0; k < 64; ++k) {
        int idx = k * 256 + tid;
        int e = idx & 15, d = idx >> 4;
        plt[e * 1024 + (d ^ (e << 2))] = proj[idx];
    }
    __syncthreads();

    const int lane = tid & 63;
    const int wid = tid >> 6;
    const int nwaves = gridDim.x * 4;
    const int ngrp = Ntok >> 1;

    for (int grp = blockIdx.x * 4 + wid; grp < ngrp; grp += nwaves) {
        const int t0 = grp * 2;
        float s[16][2];
        #pragma unroll
        for (int e = 0; e < 16; ++e) { s[e][0] = 0.f; s[e][1] = 0.f; }

        #pragma unroll
        for (int j = 0; j < 4; ++j) {
            const int d0 = (j * 64 + lane) * 4;
            float4 xq[2];
            #pragma unroll
            for (int q = 0; q < 2; ++q) {
                xq[q] = *(const float4*)&x[(size_t)(t0 + q) * 1024 + d0];
                short4 h;
                h.x = (short)f2bf(xq[q].x); h.y = (short)f2bf(xq[q].y);
                h.z = (short)f2bf(xq[q].z); h.w = (short)f2bf(xq[q].w);
                *(short4*)&xb[(size_t)(t0 + q) * 1024 + d0] = h;
            }
            #pragma unroll
            for (int e = 0; e < 16; ++e) {
                float4 p = *(const float4*)&plt[e * 1024 + (d0 ^ (e << 2))];
                #pragma unroll
                for (int q = 0; q < 2; ++q) {
                    s[e][q] = fmaf(xq[q].x, p.x, s[e][q]);
                    s[e][q] = fmaf(xq[q].y, p.y, s[e][q]);
                    s[e][q] = fmaf(xq[q].z, p.z, s[e][q]);
                    s[e][q] = fmaf(xq[q].w, p.w, s[e][q]);
                }
            }
        }
        #pragma unroll
        for (int e = 0; e < 16; ++e) {
            s[e][0] = wave_sum(s[e][0]);
            s[e][1] = wave_sum(s[e][1]);
        }
        if (lane == 63) {
            #pragma unroll
            for (int q = 0; q < 2; ++q)
                #pragma unroll
                for (int c = 0; c < 4; ++c) {
                    float4 o = { s[c * 4 + 0][q], s[c * 4 + 1][q],
                                 s[c * 4 + 2][q], s[c * 4 + 3][q] };
                    *(float4*)&sbuf[(size_t)(t0 + q) * 16 + c * 4] = o;
                }
        }
    }
}

// ---------------------------------------------------------------------------
// k1_entmax: thread-per-token LN + exact 1.5-entmax
// ---------------------------------------------------------------------------
__global__ __launch_bounds__(256)
void k1_entmax(const float* __restrict__ sbuf, float* __restrict__ abuf, int Ntok)
{
    int t = blockIdx.x * 256 + threadIdx.x;
    if (t >= Ntok) return;
    float s[16];
    #pragma unroll
    for (int c = 0; c < 4; ++c) {
        float4 v = *(const float4*)&sbuf[(size_t)t * 16 + c * 4];
        s[c * 4 + 0] = v.x; s[c * 4 + 1] = v.y; s[c * 4 + 2] = v.z; s[c * 4 + 3] = v.w;
    }
    float mean = 0.f;
    #pragma unroll
    for (int e = 0; e < 16; ++e) mean += s[e];
    mean *= 0.0625f;
    float var = 0.f;
    #pragma unroll
    for (int e = 0; e < 16; ++e) { float d = s[e] - mean; var = fmaf(d, d, var); }
    var *= 0.0625f;
    float rstd = rsqrtf(var + 1e-5f);

    float z[16];
    #pragma unroll
    for (int e = 0; e < 16; ++e) z[e] = (s[e] - mean) * rstd * 0.5f;
    float zmax = z[0];
    #pragma unroll
    for (int e = 1; e < 16; ++e) zmax = fmaxf(zmax, z[e]);
    #pragma unroll
    for (int e = 0; e < 16; ++e) z[e] -= zmax;

    float zs[16];
    #pragma unroll
    for (int e = 0; e < 16; ++e) zs[e] = z[e];
    #pragma unroll
    for (int k = 2; k <= 16; k <<= 1) {
        #pragma unroll
        for (int j = k >> 1; j > 0; j >>= 1) {
            #pragma unroll
            for (int i = 0; i < 16; ++i) {
                int l = i ^ j;
                if (l > i) {
                    float a = zs[i], b = zs[l];
                    bool asc = ((i & k) == 0);
                    bool sw = asc ? (a > b) : (a < b);
                    if (sw) { zs[i] = b; zs[l] = a; }
                }
            }
        }
    }
    float csum = 0.f, csq = 0.f, tau_star = -3.4e38f;
    #pragma unroll
    for (int kk = 1; kk <= 16; ++kk) {
        float v = zs[16 - kk];
        csum += v; csq += v * v;
        float kf = (float)kk;
        float mn = csum / kf;
        float ms = csq / kf;
        float ss = kf * (ms - mn * mn);
        float delta = fmaxf((1.f - ss) / kf, 0.f);
        float tau = mn - sqrtf(delta);
        if (tau <= v) tau_star = tau;
    }
    #pragma unroll
    for (int c = 0; c < 4; ++c) {
        float4 o;
        float p0 = fmaxf(z[c * 4 + 0] - tau_star, 0.f);
        float p1 = fmaxf(z[c * 4 + 1] - tau_star, 0.f);
        float p2 = fmaxf(z[c * 4 + 2] - tau_star, 0.f);
        float p3 = fmaxf(z[c * 4 + 3] - tau_star, 0.f);
        o.x = p0 * p0; o.y = p1 * p1; o.z = p2 * p2; o.w = p3 * p3;
        *(float4*)&abuf[(size_t)t * 16 + c * 4] = o;
    }
}

// ---------------------------------------------------------------------------
// gcompute: g1 = a@C1, g2 = a@C2 -> bf16. One wave per token.
// ---------------------------------------------------------------------------
__global__ __launch_bounds__(256)
void gcompute(const float* __restrict__ abuf, const float* __restrict__ C1,
              const float* __restrict__ C2, u16* __restrict__ g1,
              u16* __restrict__ g2, int Ntok)
{
    const int tid = threadIdx.x;
    const int lane = tid & 63;
    const int t = blockIdx.x * 4 + (tid >> 6);
    if (t >= Ntok) return;
    float a[16];
    #pragma unroll
    for (int c = 0; c < 4; ++c) {
        float4 v = *(const float4*)&abuf[(size_t)t * 16 + c * 4];
        a[c * 4 + 0] = v.x; a[c * 4 + 1] = v.y; a[c * 4 + 2] = v.z; a[c * 4 + 3] = v.w;
    }
    #pragma unroll
    for (int c8 = 0; c8 < 8; ++c8) {
        int col = c8 * 64 + lane;
        float t1 = 0.f, t2 = 0.f;
        #pragma unroll
        for (int e = 0; e < 16; ++e) {
            t1 = fmaf(a[e], C1[e * 512 + col], t1);
            t2 = fmaf(a[e], C2[e * 512 + col], t2);
        }
        g1[(size_t)t * 512 + col] = f2bf(t1);
        g2[(size_t)t * 512 + col] = f2bf(t2);
    }
}

// ---------------------------------------------------------------------------
// gemm_bt: m97 single-buffer 128x128 (proven ~694 TF, 0 conflicts). Used for
// G1/G3 (N=512: 256^2 grids too small). MODE 1: (acc+bias)*g ->bf16.
// ---------------------------------------------------------------------------
template<int MODE>
__global__ __launch_bounds__(256, 4)
void gemm_bt(const u16* __restrict__ A, const u16* __restrict__ Bt,
             const float* __restrict__ bias, const u16* __restrict__ gmat,
             void* __restrict__ Cout, int M, int Nn, int K, int tilesN)
{
    __shared__ __align__(1024) char smem[32768];
    const int tid = threadIdx.x;
    const int lane = tid & 63;
    const int wid = tid >> 6;

    int m_t, n_t;
    {
        int bid = blockIdx.x;
        int Mtiles = gridDim.x / tilesN;
        if ((Mtiles & 7) == 0) {
            int xcd = bid & 7, loc = bid >> 3;
            int lm = loc / tilesN;
            m_t = xcd * (Mtiles >> 3) + lm;
            n_t = loc - lm * tilesN;
        } else {
            m_t = bid / tilesN;
            n_t = bid % tilesN;
        }
    }
    const int m0 = m_t * 128;
    const int n0 = n_t * 128;
    const int wm = (wid >> 1) * 64;
    const int wn = (wid & 1) * 64;

    f32x4 acc[4][4];
    #pragma unroll
    for (int i = 0; i < 4; ++i)
        #pragma unroll
        for (int j = 0; j < 4; ++j) acc[i][j] = (f32x4){0.f, 0.f, 0.f, 0.f};

    const int nsteps = K >> 6;
    for (int ks = 0; ks < nsteps; ++ks) {
        const int k0 = ks << 6;
        #pragma unroll
        for (int i = 0; i < 4; ++i) {
            int q = (wid * 4 + i) * 64 + lane;
            int row = q >> 3;
            int c = (q & 7) ^ (row & 7);
            __builtin_amdgcn_global_load_lds(
                (as1_cvoid)(A + (size_t)(m0 + row) * K + k0 + c * 8),
                (as3_void)&smem[(wid * 4 + i) * 1024], 16, 0, 0);
        }
        #pragma unroll
        for (int i = 0; i < 4; ++i) {
            int q = (wid * 4 + i) * 64 + lane;
            int row = q >> 3;
            int c = (q & 7) ^ (row & 7);
            __builtin_amdgcn_global_load_lds(
                (as1_cvoid)(Bt + (size_t)(n0 + row) * K + k0 + c * 8),
                (as3_void)&smem[16384 + (wid * 4 + i) * 1024], 16, 0, 0);
        }
        __syncthreads();
        #pragma unroll
        for (int kk = 0; kk < 2; ++kk) {
            bf16x8 af[4], bfr[4];
            const int slot = kk * 4 + (lane >> 4);
            #pragma unroll
            for (int i = 0; i < 4; ++i) {
                int row = wm + i * 16 + (lane & 15);
                af[i] = *(const bf16x8*)
                    &smem[row * 128 + ((slot ^ (row & 7)) << 4)];
            }
            #pragma unroll
            for (int j = 0; j < 4; ++j) {
                int row = wn + j * 16 + (lane & 15);
                bfr[j] = *(const bf16x8*)
                    &smem[16384 + row * 128 + ((slot ^ (row & 7)) << 4)];
            }
            #pragma unroll
            for (int i = 0; i < 4; ++i)
                #pragma unroll
                for (int j = 0; j < 4; ++j)
                    acc[i][j] = MFMA16(af[i], bfr[j], acc[i][j]);
        }
        __syncthreads();
    }

    const int cl = lane & 15;
    const int rq = (lane >> 4) * 4;
    #pragma unroll
    for (int i = 0; i < 4; ++i) {
        #pragma unroll
        for (int j = 0; j < 4; ++j) {
            int col = n0 + wn + j * 16 + cl;
            float bv = (MODE == 1) ? bias[col] : 0.f;
            #pragma unroll
            for (int r = 0; r < 4; ++r) {
                int row = m0 + wm + i * 16 + rq + r;
                float v = acc[i][j][r];
                if (MODE == 0) {
                    ((u16*)Cout)[(size_t)row * Nn + col] = f2bf(gelu_fast(v));
                } else if (MODE == 1) {
                    v = (v + bv) * bf2f(gmat[(size_t)row * Nn + col]);
                    ((u16*)Cout)[(size_t)row * Nn + col] = f2bf(v);
                } else {
                    ((float*)Cout)[(size_t)row * Nn + col] = v;
                }
            }
        }
    }
}

// ---------------------------------------------------------------------------
// gemm256p: 8-phase 256x256 pipeline for big-N GEMMs (G2/G4). RACE FIX vs
// R12: boundary is vmcnt(0) — with 2 LDS buffers only ONE tile can be in
// flight, so a counted boundary wait was provably wrong (the 4 youngest
// loads were next tile's B halves, read immediately in phase 0). The early
// issue (phases 0-2, ~800 cy before the boundary) keeps the drain ~free.
// 8 waves (2Mx4N, wave-tile 128x64 -> 16 MFMA/phase), BK=64, 2x64KB dbuf,
// 4 phases/K-tile {ds_read || stage -> barrier -> lgkmcnt(0) -> setprio(1)
// 16 MFMA setprio(0) -> barrier}. XOR swizzle both-sides; M-panel XCD map.
// MODE 0: gelu->bf16; MODE 2: ->f32.
// ---------------------------------------------------------------------------
template<int MODE>
__global__ __launch_bounds__(512, 1)
void gemm256p(const u16* __restrict__ A, const u16* __restrict__ Bt,
              void* __restrict__ Cout, int M, int Nn, int K, int tilesN)
{
    __shared__ __align__(1024) char smem[131072];  // 2 x (A 32K + B 32K)
    const int tid = threadIdx.x;
    const int lane = tid & 63;
    const int wid = tid >> 6;
    const int wr = wid >> 2;          // 0..1
    const int wc = wid & 3;           // 0..3

    int m_t, n_t;
    {
        int bid = blockIdx.x;
        int Mtiles = gridDim.x / tilesN;
        if ((Mtiles & 7) == 0) {
            int xcd = bid & 7, loc = bid >> 3;
            int lm = loc / tilesN;
            m_t = xcd * (Mtiles >> 3) + lm;
            n_t = loc - lm * tilesN;
        } else {
            m_t = bid / tilesN;
            n_t = bid % tilesN;
        }
    }
    const int m0 = m_t * 256;
    const int n0 = n_t * 256;

    f32x4 acc[8][4];
    #pragma unroll
    for (int i = 0; i < 8; ++i)
        #pragma unroll
        for (int j = 0; j < 4; ++j) acc[i][j] = (f32x4){0.f, 0.f, 0.f, 0.f};

    // staging pointers: halves h, gloads i; q = h*1024 + i*512 + tid
    const u16* gA[2][2];
    const u16* gB[2][2];
    #pragma unroll
    for (int h = 0; h < 2; ++h)
        #pragma unroll
        for (int i = 0; i < 2; ++i) {
            int q = h * 1024 + i * 512 + tid;
            int row = q >> 3;
            int c = (q & 7) ^ (row & 7);
            gA[h][i] = A + (size_t)(m0 + row) * K + c * 8;
            gB[h][i] = Bt + (size_t)(n0 + row) * K + c * 8;
        }
    const int dbase = wid * 1024;   // wave-uniform component of LDS dest

    auto stA = [&](int b, int h, int i) {
        __builtin_amdgcn_global_load_lds((as1_cvoid)gA[h][i],
            (as3_void)&smem[b * 32768 + h * 16384 + i * 8192 + dbase], 16, 0, 0);
        gA[h][i] += 64;
    };
    auto stB = [&](int b, int h, int i) {
        __builtin_amdgcn_global_load_lds((as1_cvoid)gB[h][i],
            (as3_void)&smem[65536 + b * 32768 + h * 16384 + i * 8192 + dbase], 16, 0, 0);
        gB[h][i] += 64;
    };

    const int arow = wr * 128 + (lane & 15);
    const int brow = wc * 64 + (lane & 15);
    const int sHi = lane >> 4;
    auto LDA = [&](int b, int i, int kk) -> bf16x8 {
        int row = arow + i * 16;
        return *(const bf16x8*)&smem[b * 32768 + row * 128
            + ((((kk << 2) | sHi) ^ (row & 7)) << 4)];
    };
    auto LDB = [&](int b, int j, int kk) -> bf16x8 {
        int row = brow + j * 16;
        return *(const bf16x8*)&smem[65536 + b * 32768 + row * 128
            + ((((kk << 2) | sHi) ^ (row & 7)) << 4)];
    };

    const int nt = K >> 6;
    // prologue: stage tile 0 fully, drain once, barrier
    stA(0, 0, 0); stA(0, 0, 1); stA(0, 1, 0); stA(0, 1, 1);
    stB(0, 0, 0); stB(0, 0, 1); stB(0, 1, 0); stB(0, 1, 1);
    asm volatile("s_waitcnt vmcnt(0)" ::: "memory");
    __builtin_amdgcn_sched_barrier(0);
    __builtin_amdgcn_s_barrier();

    for (int t = 0; t < nt; ++t) {
        const int b = t & 1;
        const bool st = (t + 1) < nt;
        bf16x8 aR[4], bR[4];

        // ---- phase 0: B kk0 + A i0-3 kk0; stage next A-half0+half1 ----
        bR[0] = LDB(b, 0, 0); bR[1] = LDB(b, 1, 0);
        bR[2] = LDB(b, 2, 0); bR[3] = LDB(b, 3, 0);
        aR[0] = LDA(b, 0, 0); aR[1] = LDA(b, 1, 0);
        aR[2] = LDA(b, 2, 0); aR[3] = LDA(b, 3, 0);
        if (st) { stA(b ^ 1, 0, 0); stA(b ^ 1, 0, 1);
                  stA(b ^ 1, 1, 0); stA(b ^ 1, 1, 1); }
        __builtin_amdgcn_s_barrier();
        asm volatile("s_waitcnt lgkmcnt(0)" ::: "memory");
        __builtin_amdgcn_sched_barrier(0);
        __builtin_amdgcn_s_setprio(1);
        #pragma unroll
        for (int i = 0; i < 4; ++i)
            #pragma unroll
            for (int j = 0; j < 4; ++j)
                acc[i][j] = MFMA16(aR[i], bR[j], acc[i][j]);
        __builtin_amdgcn_s_setprio(0);
        __builtin_amdgcn_s_barrier();

        // ---- phase 1: A i4-7 kk0; stage next B-half0 ----
        aR[0] = LDA(b, 4, 0); aR[1] = LDA(b, 5, 0);
        aR[2] = LDA(b, 6, 0); aR[3] = LDA(b, 7, 0);
        if (st) { stB(b ^ 1, 0, 0); stB(b ^ 1, 0, 1); }
        __builtin_amdgcn_s_barrier();
        asm volatile("s_waitcnt lgkmcnt(0)" ::: "memory");
        __builtin_amdgcn_sched_barrier(0);
        __builtin_amdgcn_s_setprio(1);
        #pragma unroll
        for (int i = 0; i < 4; ++i)
            #pragma unroll
            for (int j = 0; j < 4; ++j)
                acc[4 + i][j] = MFMA16(aR[i], bR[j], acc[4 + i][j]);
        __builtin_amdgcn_s_setprio(0);
        __builtin_amdgcn_s_barrier();

        // ---- phase 2: B kk1 + A i0-3 kk1; stage next B-half1 ----
        bR[0] = LDB(b, 0, 1); bR[1] = LDB(b, 1, 1);
        bR[2] = LDB(b, 2, 1); bR[3] = LDB(b, 3, 1);
        aR[0] = LDA(b, 0, 1); aR[1] = LDA(b, 1, 1);
        aR[2] = LDA(b, 2, 1); aR[3] = LDA(b, 3, 1);
        if (st) { stB(b ^ 1, 1, 0); stB(b ^ 1, 1, 1); }
        __builtin_amdgcn_s_barrier();
        asm volatile("s_waitcnt lgkmcnt(0)" ::: "memory");
        __builtin_amdgcn_sched_barrier(0);
        __builtin_amdgcn_s_setprio(1);
        #pragma unroll
        for (int i = 0; i < 4; ++i)
            #pragma unroll
            for (int j = 0; j < 4; ++j)
                acc[i][j] = MFMA16(aR[i], bR[j], acc[i][j]);
        __builtin_amdgcn_s_setprio(0);
        __builtin_amdgcn_s_barrier();

        // ---- phase 3: A i4-7 kk1; boundary: vmcnt(0) (sole tile in flight,
        // issued >=2 phases ago -> wait is ~free) ----
        aR[0] = LDA(b, 4, 1); aR[1] = LDA(b, 5, 1);
        aR[2] = LDA(b, 6, 1); aR[3] = LDA(b, 7, 1);
        __builtin_amdgcn_s_barrier();
        asm volatile("s_waitcnt lgkmcnt(0)" ::: "memory");
        __builtin_amdgcn_sched_barrier(0);
        __builtin_amdgcn_s_setprio(1);
        #pragma unroll
        for (int i = 0; i < 4; ++i)
            #pragma unroll
            for (int j = 0; j < 4; ++j)
                acc[4 + i][j] = MFMA16(aR[i], bR[j], acc[4 + i][j]);
        __builtin_amdgcn_s_setprio(0);
        if (st) asm volatile("s_waitcnt vmcnt(0)" ::: "memory");
        __builtin_amdgcn_sched_barrier(0);
        __builtin_amdgcn_s_barrier();
    }

    // epilogue: C/D layout col=lane&15, row=(lane>>4)*4 + r
    const int cl = lane & 15;
    const int rq = (lane >> 4) * 4;
    #pragma unroll
    for (int i = 0; i < 8; ++i) {
        #pragma unroll
        for (int j = 0; j < 4; ++j) {
            int col = n0 + wc * 64 + j * 16 + cl;
            #pragma unroll
            for (int r = 0; r < 4; ++r) {
                int row = m0 + wr * 128 + i * 16 + rq + r;
                float v = acc[i][j][r];
                if (MODE == 0) {
                    ((u16*)Cout)[(size_t)row * Nn + col] = f2bf(gelu_fast(v));
                } else {
                    ((float*)Cout)[(size_t)row * Nn + col] = v;
                }
            }
        }
    }
}

// ---------------------------------------------------------------------------
extern "C" void kernel_launch(void* const* d_in, const int* in_sizes, int n_in,
                              void* d_out, int out_size, void* d_ws, size_t ws_size,
                              hipStream_t stream)
{
    const float* x     = (const float*)d_in[0];
    const float* proj  = (const float*)d_in[1];
    const float* C1    = (const float*)d_in[2];
    const float* Win1  = (const float*)d_in[3];
    const float* Wout1 = (const float*)d_in[4];
    const float* C2    = (const float*)d_in[5];
    const float* Win2  = (const float*)d_in[6];
    const float* Wout2 = (const float*)d_in[7];

    const int D = 1024, O = 4096, R = 512, D2 = 1024;
    const int Ntok = in_sizes[0] / D;   // 16384

    char* ws = (char*)d_ws;
    size_t off = 0;
    auto alloc = [&](size_t bytes) -> void* {
        void* p = ws + off;
        off += (bytes + 255) & ~(size_t)255;
        return p;
    };
    // ---- persistent ----
    u16*   z1  = (u16*)  alloc((size_t)Ntok * R * 2);    // aliases g1
    u16*   z2  = (u16*)  alloc((size_t)Ntok * R * 2);    // aliases g2
    u16*   w1o = (u16*)  alloc((size_t)O * R * 2);       // Wout1  [4096,512]
    u16*   w2t = (u16*)  alloc((size_t)R * O * 2);       // Win2^T [512,4096]
    u16*   w2o = (u16*)  alloc((size_t)D2 * R * 2);      // Wout2  [1024,512]
    float* b1  = (float*)alloc(R * 4);
    float* b2  = (float*)alloc(R * 4);
    size_t persist_end = off;

    // ---- transient (dead before first G2) ----
    u16*   xb   = (u16*)  alloc((size_t)Ntok * D * 2);
    u16*   w1t  = (u16*)  alloc((size_t)R * D * 2);      // Win1^T [512,1024]
    float* sbuf = (float*)alloc((size_t)Ntok * 16 * 4);
    float* abuf = (float*)alloc((size_t)Ntok * 16 * 4);

    // hbuf overlays the transient region; chunk rows multiple of 1024
    size_t hAvail = (ws_size > persist_end) ? (ws_size - persist_end) : 0;
    long long chRows = (long long)(hAvail / ((size_t)O * 2));
    chRows &= ~1023LL;
    int CH = (chRows > Ntok) ? Ntok : (int)chRows;
    if (CH < 1024) CH = 1024;
    u16* hbuf = (u16*)(ws + persist_end);

    u16* g1 = z1;
    u16* g2 = z2;

    // weight prep
    prep_transpose<<<(D / 32) * (R / 32), 256, 0, stream>>>(Win1, w1t, R, D);
    prep_transpose<<<(O / 32) * (R / 32), 256, 0, stream>>>(Win2, w2t, R, O);
    prep_cast<<<(O * R + 255) / 256, 256, 0, stream>>>(
        Win1, Wout1, Win2, Wout2, w1o, w2o, b1, b2);

    // gating path
    k1_proj  <<<512, 256, 0, stream>>>(x, proj, xb, sbuf, Ntok);
    k1_entmax<<<(Ntok + 255) / 256, 256, 0, stream>>>(sbuf, abuf, Ntok);
    gcompute <<<(Ntok + 3) / 4, 256, 0, stream>>>(abuf, C1, C2, g1, g2, Ntok);

    // G1: z1 = (x @ Win1 + b1) * g1   [N,512], K=1024  (in-place over g1)
    gemm_bt<1><<<(Ntok / 128) * (R / 128), 256, 0, stream>>>(
        xb, w1t, b1, g1, z1, Ntok, R, D, R / 128);

    // chunked: G2: h = gelu(z1 @ Wout1^T) [N,4096], K=512  (8-phase 256^2)
    //          G3: z2 = (h @ Win2 + b2) * g2 [N,512], K=4096 (in-place, 128^2)
    for (int r0 = 0; r0 < Ntok; r0 += CH) {
        int cm = Ntok - r0; if (cm > CH) cm = CH;
        gemm256p<0><<<(cm / 256) * (O / 256), 512, 0, stream>>>(
            z1 + (size_t)r0 * R, w1o, hbuf, cm, O, R, O / 256);
        gemm_bt<1><<<(cm / 128) * (R / 128), 256, 0, stream>>>(
            hbuf, w2t, b2, g2 + (size_t)r0 * R,
            z2 + (size_t)r0 * R, cm, R, O, R / 128);
    }

    // G4: out = z2 @ Wout2^T  [N,1024] f32, K=512  (8-phase 256^2)
    gemm256p<2><<<(Ntok / 256) * (D2 / 256), 512, 0, stream>>>(
        z2, w2o, d_out, Ntok, D2, R, D2 / 256);
}

// Round 14
// 324.022 us; speedup vs baseline: 1.0395x; 1.0395x over previous
//
#include <hip/hip_runtime.h>
#include <hip/hip_bf16.h>
#include <math.h>
#include <stdint.h>

typedef unsigned short u16;
typedef __attribute__((ext_vector_type(8))) short bf16x8;
typedef __attribute__((ext_vector_type(4))) float f32x4;
typedef __attribute__((address_space(3))) void* as3_void;
typedef const __attribute__((address_space(1))) void* as1_cvoid;

__device__ inline u16 f2bf(float f) {
    union { float f; unsigned u; } v; v.f = f;
    unsigned r = v.u + 0x7FFFu + ((v.u >> 16) & 1u);   // round-to-nearest-even
    return (u16)(r >> 16);
}
__device__ inline float bf2f(u16 h) {
    unsigned u = ((unsigned)h) << 16;
    return __builtin_bit_cast(float, u);
}
// fast GELU (tanh form via sigmoid): x * sigma(1.5957691*(x+0.044715x^3))
__device__ inline float gelu_fast(float v) {
    float t = v * fmaf(0.07135702f, v * v, 1.5957691f);
    return v / (1.f + __expf(-t));
}

// DPP helper
template<int CTRL, int RM>
__device__ inline float dpp_mov(float v) {
    return __builtin_bit_cast(float, __builtin_amdgcn_update_dpp(
        0, __builtin_bit_cast(int, v), CTRL, RM, 0xf, false));
}
__device__ inline float wave_sum(float v) {
    v += dpp_mov<0x111, 0xf>(v);
    v += dpp_mov<0x112, 0xf>(v);
    v += dpp_mov<0x114, 0xf>(v);
    v += dpp_mov<0x118, 0xf>(v);
    v += dpp_mov<0x142, 0xa>(v);
    v += dpp_mov<0x143, 0xc>(v);
    return v;                      // lane 63 holds total
}

// ---------------------------------------------------------------------------
// prep_all: all weight prep in ONE kernel (transposes + bf16 casts + biases)
// ---------------------------------------------------------------------------
__global__ __launch_bounds__(256)
void prep_all(const float* __restrict__ Win1, const float* __restrict__ Wout1,
              const float* __restrict__ Win2, const float* __restrict__ Wout2,
              u16* __restrict__ w1t, u16* __restrict__ w1o,
              u16* __restrict__ w2t, u16* __restrict__ w2o,
              float* __restrict__ b1, float* __restrict__ b2)
{
    int idx = blockIdx.x * 256 + threadIdx.x;
    if (idx < 524288) {            // w1t[r][d] = Win1[d][r], D=1024 R=512
        int r = idx >> 10, d = idx & 1023;
        w1t[idx] = f2bf(Win1[(size_t)d * 512 + r]);
    }
    if (idx < 2097152) {           // w1o = bf16(Wout1), [4096,512]
        w1o[idx] = f2bf(Wout1[idx]);
    }
    if (idx < 2097152) {           // w2t[r][o] = Win2[o][r], O=4096 R=512
        int r = idx >> 12, o = idx & 4095;
        w2t[idx] = f2bf(Win2[(size_t)o * 512 + r]);
    }
    if (idx < 524288) {            // w2o = bf16(Wout2), [1024,512]
        w2o[idx] = f2bf(Wout2[idx]);
    }
    if (idx < 512) {
        b1[idx] = Win1[(size_t)1024 * 512 + idx];
        b2[idx] = Win2[(size_t)4096 * 512 + idx];
    }
}

// ---------------------------------------------------------------------------
// k1_proj: s = x@proj (f32) + x->bf16 cast. 2 tokens per wave.
// ---------------------------------------------------------------------------
__global__ __launch_bounds__(256)
void k1_proj(const float* __restrict__ x, const float* __restrict__ proj,
             u16* __restrict__ xb, float* __restrict__ sbuf, int Ntok)
{
    __shared__ float plt[16 * 1024];
    const int tid = threadIdx.x;
    #pragma unroll
    for (int k = 0; k < 64; ++k) {
        int idx = k * 256 + tid;
        int e = idx & 15, d = idx >> 4;
        plt[e * 1024 + (d ^ (e << 2))] = proj[idx];
    }
    __syncthreads();

    const int lane = tid & 63;
    const int wid = tid >> 6;
    const int t0 = (blockIdx.x * 4 + wid) * 2;
    if (t0 >= Ntok) return;

    float s[16][2];
    #pragma unroll
    for (int e = 0; e < 16; ++e) { s[e][0] = 0.f; s[e][1] = 0.f; }

    #pragma unroll
    for (int j = 0; j < 4; ++j) {
        const int d0 = (j * 64 + lane) * 4;
        float4 xq[2];
        #pragma unroll
        for (int q = 0; q < 2; ++q) {
            xq[q] = *(const float4*)&x[(size_t)(t0 + q) * 1024 + d0];
            short4 h;
            h.x = (short)f2bf(xq[q].x); h.y = (short)f2bf(xq[q].y);
            h.z = (short)f2bf(xq[q].z); h.w = (short)f2bf(xq[q].w);
            *(short4*)&xb[(size_t)(t0 + q) * 1024 + d0] = h;
        }
        #pragma unroll
        for (int e = 0; e < 16; ++e) {
            float4 p = *(const float4*)&plt[e * 1024 + (d0 ^ (e << 2))];
            #pragma unroll
            for (int q = 0; q < 2; ++q) {
                s[e][q] = fmaf(xq[q].x, p.x, s[e][q]);
                s[e][q] = fmaf(xq[q].y, p.y, s[e][q]);
                s[e][q] = fmaf(xq[q].z, p.z, s[e][q]);
                s[e][q] = fmaf(xq[q].w, p.w, s[e][q]);
            }
        }
    }
    #pragma unroll
    for (int e = 0; e < 16; ++e) {
        s[e][0] = wave_sum(s[e][0]);
        s[e][1] = wave_sum(s[e][1]);
    }
    if (lane == 63) {
        #pragma unroll
        for (int q = 0; q < 2; ++q)
            #pragma unroll
            for (int c = 0; c < 4; ++c) {
                float4 o = { s[c * 4 + 0][q], s[c * 4 + 1][q],
                             s[c * 4 + 2][q], s[c * 4 + 3][q] };
                *(float4*)&sbuf[(size_t)(t0 + q) * 16 + c * 4] = o;
            }
    }
}

// ---------------------------------------------------------------------------
// k1_entmax: thread-per-token LN + exact 1.5-entmax
// ---------------------------------------------------------------------------
__global__ __launch_bounds__(256)
void k1_entmax(const float* __restrict__ sbuf, float* __restrict__ abuf, int Ntok)
{
    int t = blockIdx.x * 256 + threadIdx.x;
    if (t >= Ntok) return;
    float s[16];
    #pragma unroll
    for (int c = 0; c < 4; ++c) {
        float4 v = *(const float4*)&sbuf[(size_t)t * 16 + c * 4];
        s[c * 4 + 0] = v.x; s[c * 4 + 1] = v.y; s[c * 4 + 2] = v.z; s[c * 4 + 3] = v.w;
    }
    float mean = 0.f;
    #pragma unroll
    for (int e = 0; e < 16; ++e) mean += s[e];
    mean *= 0.0625f;
    float var = 0.f;
    #pragma unroll
    for (int e = 0; e < 16; ++e) { float d = s[e] - mean; var = fmaf(d, d, var); }
    var *= 0.0625f;
    float rstd = rsqrtf(var + 1e-5f);

    float z[16];
    #pragma unroll
    for (int e = 0; e < 16; ++e) z[e] = (s[e] - mean) * rstd * 0.5f;
    float zmax = z[0];
    #pragma unroll
    for (int e = 1; e < 16; ++e) zmax = fmaxf(zmax, z[e]);
    #pragma unroll
    for (int e = 0; e < 16; ++e) z[e] -= zmax;

    float zs[16];
    #pragma unroll
    for (int e = 0; e < 16; ++e) zs[e] = z[e];
    #pragma unroll
    for (int k = 2; k <= 16; k <<= 1) {
        #pragma unroll
        for (int j = k >> 1; j > 0; j >>= 1) {
            #pragma unroll
            for (int i = 0; i < 16; ++i) {
                int l = i ^ j;
                if (l > i) {
                    float a = zs[i], b = zs[l];
                    bool asc = ((i & k) == 0);
                    bool sw = asc ? (a > b) : (a < b);
                    if (sw) { zs[i] = b; zs[l] = a; }
                }
            }
        }
    }
    float csum = 0.f, csq = 0.f, tau_star = -3.4e38f;
    #pragma unroll
    for (int kk = 1; kk <= 16; ++kk) {
        float v = zs[16 - kk];
        csum += v; csq += v * v;
        float kf = (float)kk;
        float mn = csum / kf;
        float ms = csq / kf;
        float ss = kf * (ms - mn * mn);
        float delta = fmaxf((1.f - ss) / kf, 0.f);
        float tau = mn - sqrtf(delta);
        if (tau <= v) tau_star = tau;
    }
    #pragma unroll
    for (int c = 0; c < 4; ++c) {
        float4 o;
        float p0 = fmaxf(z[c * 4 + 0] - tau_star, 0.f);
        float p1 = fmaxf(z[c * 4 + 1] - tau_star, 0.f);
        float p2 = fmaxf(z[c * 4 + 2] - tau_star, 0.f);
        float p3 = fmaxf(z[c * 4 + 3] - tau_star, 0.f);
        o.x = p0 * p0; o.y = p1 * p1; o.z = p2 * p2; o.w = p3 * p3;
        *(float4*)&abuf[(size_t)t * 16 + c * 4] = o;
    }
}

// ---------------------------------------------------------------------------
// gcompute: g1 = a@C1, g2 = a@C2 -> bf16. One wave per token.
// ---------------------------------------------------------------------------
__global__ __launch_bounds__(256)
void gcompute(const float* __restrict__ abuf, const float* __restrict__ C1,
              const float* __restrict__ C2, u16* __restrict__ g1,
              u16* __restrict__ g2, int Ntok)
{
    const int tid = threadIdx.x;
    const int lane = tid & 63;
    const int t = blockIdx.x * 4 + (tid >> 6);
    if (t >= Ntok) return;
    float a[16];
    #pragma unroll
    for (int c = 0; c < 4; ++c) {
        float4 v = *(const float4*)&abuf[(size_t)t * 16 + c * 4];
        a[c * 4 + 0] = v.x; a[c * 4 + 1] = v.y; a[c * 4 + 2] = v.z; a[c * 4 + 3] = v.w;
    }
    #pragma unroll
    for (int c8 = 0; c8 < 8; ++c8) {
        int col = c8 * 64 + lane;
        float t1 = 0.f, t2 = 0.f;
        #pragma unroll
        for (int e = 0; e < 16; ++e) {
            t1 = fmaf(a[e], C1[e * 512 + col], t1);
            t2 = fmaf(a[e], C2[e * 512 + col], t2);
        }
        g1[(size_t)t * 512 + col] = f2bf(t1);
        g2[(size_t)t * 512 + col] = f2bf(t2);
    }
}

// ---------------------------------------------------------------------------
// gemm_bt: m97 single-buffer structure — the best-measured configuration
// across 13 rounds (R7 kernel, 324.3 us total). 128x128 tile, 4 waves,
// BK=64, 32 KB LDS, 16x16x32 MFMA, zero-conflict XOR swizzle (both-sides),
// M-panel-per-XCD mapping, scalar epilogue. A/B'd and rejected: 8-phase
// 256^2 (-6..15% at K<=1024), 32x32 MFMA (bank conflicts), LDS-bounce
// epilogue (-6%), explicit dbuf/deep pipelines (occupancy loss).
// MODE 0: fast-gelu->bf16; MODE 1: (acc+bias)*g ->bf16 (g bf16, may alias
// Cout); MODE 2: ->f32.
// ---------------------------------------------------------------------------
template<int MODE>
__global__ __launch_bounds__(256, 4)
void gemm_bt(const u16* __restrict__ A, const u16* __restrict__ Bt,
             const float* __restrict__ bias, const u16* __restrict__ gmat,
             void* __restrict__ Cout, int M, int Nn, int K, int tilesN)
{
    __shared__ __align__(1024) char smem[32768];   // A 16KB + B 16KB
    const int tid = threadIdx.x;
    const int lane = tid & 63;
    const int wid = tid >> 6;

    // M-panel-per-XCD mapping
    int m_t, n_t;
    {
        int bid = blockIdx.x;
        int Mtiles = gridDim.x / tilesN;
        if ((Mtiles & 7) == 0) {
            int xcd = bid & 7, loc = bid >> 3;
            int lm = loc / tilesN;
            m_t = xcd * (Mtiles >> 3) + lm;
            n_t = loc - lm * tilesN;
        } else {
            m_t = bid / tilesN;
            n_t = bid % tilesN;
        }
    }
    const int m0 = m_t * 128;
    const int n0 = n_t * 128;
    const int wm = (wid >> 1) * 64;
    const int wn = (wid & 1) * 64;

    f32x4 acc[4][4];
    #pragma unroll
    for (int i = 0; i < 4; ++i)
        #pragma unroll
        for (int j = 0; j < 4; ++j) acc[i][j] = (f32x4){0.f, 0.f, 0.f, 0.f};

    const int nsteps = K >> 6;
    for (int ks = 0; ks < nsteps; ++ks) {
        const int k0 = ks << 6;
        // stage A/B tiles [128][64]; linear LDS dest, source chunk XOR-swizzled
        #pragma unroll
        for (int i = 0; i < 4; ++i) {
            int q = (wid * 4 + i) * 64 + lane;
            int row = q >> 3;
            int c = (q & 7) ^ (row & 7);
            __builtin_amdgcn_global_load_lds(
                (as1_cvoid)(A + (size_t)(m0 + row) * K + k0 + c * 8),
                (as3_void)&smem[(wid * 4 + i) * 1024], 16, 0, 0);
        }
        #pragma unroll
        for (int i = 0; i < 4; ++i) {
            int q = (wid * 4 + i) * 64 + lane;
            int row = q >> 3;
            int c = (q & 7) ^ (row & 7);
            __builtin_amdgcn_global_load_lds(
                (as1_cvoid)(Bt + (size_t)(n0 + row) * K + k0 + c * 8),
                (as3_void)&smem[16384 + (wid * 4 + i) * 1024], 16, 0, 0);
        }
        __syncthreads();
        #pragma unroll
        for (int kk = 0; kk < 2; ++kk) {
            bf16x8 af[4], bfr[4];
            const int slot = kk * 4 + (lane >> 4);
            #pragma unroll
            for (int i = 0; i < 4; ++i) {
                int row = wm + i * 16 + (lane & 15);
                af[i] = *(const bf16x8*)
                    &smem[row * 128 + ((slot ^ (row & 7)) << 4)];
            }
            #pragma unroll
            for (int j = 0; j < 4; ++j) {
                int row = wn + j * 16 + (lane & 15);
                bfr[j] = *(const bf16x8*)
                    &smem[16384 + row * 128 + ((slot ^ (row & 7)) << 4)];
            }
            #pragma unroll
            for (int i = 0; i < 4; ++i)
                #pragma unroll
                for (int j = 0; j < 4; ++j)
                    acc[i][j] = __builtin_amdgcn_mfma_f32_16x16x32_bf16(
                        af[i], bfr[j], acc[i][j], 0, 0, 0);
        }
        __syncthreads();
    }

    const int cl = lane & 15;
    const int rq = (lane >> 4) * 4;
    #pragma unroll
    for (int i = 0; i < 4; ++i) {
        #pragma unroll
        for (int j = 0; j < 4; ++j) {
            int col = n0 + wn + j * 16 + cl;
            float bv = (MODE == 1) ? bias[col] : 0.f;
            #pragma unroll
            for (int r = 0; r < 4; ++r) {
                int row = m0 + wm + i * 16 + rq + r;
                float v = acc[i][j][r];
                if (MODE == 0) {
                    ((u16*)Cout)[(size_t)row * Nn + col] = f2bf(gelu_fast(v));
                } else if (MODE == 1) {
                    v = (v + bv) * bf2f(gmat[(size_t)row * Nn + col]);
                    ((u16*)Cout)[(size_t)row * Nn + col] = f2bf(v);
                } else {
                    ((float*)Cout)[(size_t)row * Nn + col] = v;
                }
            }
        }
    }
}

// ---------------------------------------------------------------------------
extern "C" void kernel_launch(void* const* d_in, const int* in_sizes, int n_in,
                              void* d_out, int out_size, void* d_ws, size_t ws_size,
                              hipStream_t stream)
{
    const float* x     = (const float*)d_in[0];
    const float* proj  = (const float*)d_in[1];
    const float* C1    = (const float*)d_in[2];
    const float* Win1  = (const float*)d_in[3];
    const float* Wout1 = (const float*)d_in[4];
    const float* C2    = (const float*)d_in[5];
    const float* Win2  = (const float*)d_in[6];
    const float* Wout2 = (const float*)d_in[7];

    const int D = 1024, O = 4096, R = 512, D2 = 1024;
    const int Ntok = in_sizes[0] / D;   // 16384

    char* ws = (char*)d_ws;
    size_t off = 0;
    auto alloc = [&](size_t bytes) -> void* {
        void* p = ws + off;
        off += (bytes + 255) & ~(size_t)255;
        return p;
    };
    // ---- persistent ----
    u16*   z1  = (u16*)  alloc((size_t)Ntok * R * 2);    // aliases g1
    u16*   z2  = (u16*)  alloc((size_t)Ntok * R * 2);    // aliases g2
    u16*   w1o = (u16*)  alloc((size_t)O * R * 2);       // Wout1  [4096,512]
    u16*   w2t = (u16*)  alloc((size_t)R * O * 2);       // Win2^T [512,4096]
    u16*   w2o = (u16*)  alloc((size_t)D2 * R * 2);      // Wout2  [1024,512]
    float* b1  = (float*)alloc(R * 4);
    float* b2  = (float*)alloc(R * 4);
    size_t persist_end = off;

    // ---- transient (dead before first G2) ----
    u16*   xb   = (u16*)  alloc((size_t)Ntok * D * 2);
    u16*   w1t  = (u16*)  alloc((size_t)R * D * 2);      // Win1^T [512,1024]
    float* sbuf = (float*)alloc((size_t)Ntok * 16 * 4);
    float* abuf = (float*)alloc((size_t)Ntok * 16 * 4);

    // hbuf overlays the transient region; chunk rows multiple of 1024 so the
    // per-chunk Mtiles stays divisible by 8 (M-panel XCD mapping)
    size_t hAvail = (ws_size > persist_end) ? (ws_size - persist_end) : 0;
    long long chRows = (long long)(hAvail / ((size_t)O * 2));
    chRows &= ~1023LL;
    int CH = (chRows > Ntok) ? Ntok : (int)chRows;
    if (CH < 1024) CH = 1024;
    u16* hbuf = (u16*)(ws + persist_end);

    u16* g1 = z1;
    u16* g2 = z2;

    // fused weight prep (one launch)
    prep_all<<<(O * R + 255) / 256, 256, 0, stream>>>(
        Win1, Wout1, Win2, Wout2, w1t, w1o, w2t, w2o, b1, b2);

    // gating path
    k1_proj  <<<Ntok / 8, 256, 0, stream>>>(x, proj, xb, sbuf, Ntok);
    k1_entmax<<<(Ntok + 255) / 256, 256, 0, stream>>>(sbuf, abuf, Ntok);
    gcompute <<<(Ntok + 3) / 4, 256, 0, stream>>>(abuf, C1, C2, g1, g2, Ntok);

    // G1: z1 = (x @ Win1 + b1) * g1   [N,512], K=1024  (in-place over g1)
    gemm_bt<1><<<(Ntok / 128) * (R / 128), 256, 0, stream>>>(
        xb, w1t, b1, g1, z1, Ntok, R, D, R / 128);

    // chunked: G2: h = gelu(z1 @ Wout1^T) [N,4096], K=512
    //          G3: z2 = (h @ Win2 + b2) * g2 [N,512], K=4096 (in-place)
    for (int r0 = 0; r0 < Ntok; r0 += CH) {
        int cm = Ntok - r0; if (cm > CH) cm = CH;
        gemm_bt<0><<<(cm / 128) * (O / 128), 256, 0, stream>>>(
            z1 + (size_t)r0 * R, w1o, nullptr, nullptr,
            hbuf, cm, O, R, O / 128);
        gemm_bt<1><<<(cm / 128) * (R / 128), 256, 0, stream>>>(
            hbuf, w2t, b2, g2 + (size_t)r0 * R,
            z2 + (size_t)r0 * R, cm, R, O, R / 128);
    }

    // G4: out = z2 @ Wout2^T  [N,1024] f32, K=512
    gemm_bt<2><<<(Ntok / 128) * (D2 / 128), 256, 0, stream>>>(
        z2, w2o, nullptr, nullptr, d_out, Ntok, D2, R, D2 / 128);
}